// Round 1
// baseline (134.343 us; speedup 1.0000x reference)
//
#include <hip/hip_runtime.h>

namespace {
constexpr int N_ELEMS = 262144;
constexpr int N_NODES = 263169;

// folded material constants (fp32, match reference math)
constexpr float GC_2L0  = 0.09f;          // G_C / (2*L_0)
constexpr float L0SQ    = 0.015f * 0.015f;
constexpr float MU_     = 80.76923076923077f;   // E/(2(1+nu))
constexpr float K_MOD   = 175.0f;               // lam + 2mu/3 (exact)
constexpr float PENALTY = 1799.82f;             // G_C/L_0*(1/PF_TOL^2-1)
}

__device__ __forceinline__ float waveReduce(float x) {
#pragma unroll
    for (int off = 32; off; off >>= 1) x += __shfl_down(x, off, 64);
    return x;
}

__global__ __launch_bounds__(256) void elem_energy(
    const float* __restrict__ u, const float* __restrict__ v,
    const float* __restrict__ c, const int* __restrict__ conn,
    const float* __restrict__ Nf, const float* __restrict__ dNdx,
    const float* __restrict__ B, const float* __restrict__ vol,
    float* __restrict__ out)
{
    const int e = blockIdx.x * blockDim.x + threadIdx.x;
    float Eel = 0.f, Efr = 0.f;
    if (e < N_ELEMS) {
        const int4 cn = *reinterpret_cast<const int4*>(conn + 4ll * e);
        const float c0 = c[cn.x], c1 = c[cn.y], c2 = c[cn.z], c3 = c[cn.w];
        const float uv0 = u[cn.x], uv1 = v[cn.x];
        const float uv2 = u[cn.y], uv3 = v[cn.y];
        const float uv4 = u[cn.z], uv5 = v[cn.z];
        const float uv6 = u[cn.w], uv7 = v[cn.w];
        const float o0 = 1.f - c0, o1 = 1.f - c1, o2 = 1.f - c2, o3 = 1.f - c3;

        const float4* __restrict__ Np = reinterpret_cast<const float4*>(Nf   + 16ll * e);
        const float4* __restrict__ Dp = reinterpret_cast<const float4*>(dNdx + 32ll * e);
        const float4* __restrict__ Bp = reinterpret_cast<const float4*>(B    + 96ll * e);
        const float4 vv = *reinterpret_cast<const float4*>(vol + 4ll * e);
        const float volA[4] = {vv.x, vv.y, vv.z, vv.w};

#pragma unroll
        for (int ip = 0; ip < 4; ++ip) {
            // degradation + fracture density
            const float4 Nr = Np[ip];
            const float omc = Nr.x * o0 + Nr.y * o1 + Nr.z * o2 + Nr.w * o3;
            const float g   = omc * omc;
            const float cip = 1.f - omc;
            const float4 dx = Dp[2 * ip], dy = Dp[2 * ip + 1];
            const float gx = dx.x * c0 + dx.y * c1 + dx.z * c2 + dx.w * c3;
            const float gy = dy.x * c0 + dy.y * c1 + dy.z * c2 + dy.w * c3;
            const float fr = GC_2L0 * (cip * cip + L0SQ * (gx * gx + gy * gy));
            Efr += fr * volA[ip];

            // strain via B
            const float4 b0 = Bp[6 * ip + 0], b1 = Bp[6 * ip + 1];
            const float4 b2 = Bp[6 * ip + 2], b3 = Bp[6 * ip + 3];
            const float4 b4 = Bp[6 * ip + 4], b5 = Bp[6 * ip + 5];
            const float exx = b0.x * uv0 + b0.y * uv1 + b0.z * uv2 + b0.w * uv3
                            + b1.x * uv4 + b1.y * uv5 + b1.z * uv6 + b1.w * uv7;
            const float eyy = b2.x * uv0 + b2.y * uv1 + b2.z * uv2 + b2.w * uv3
                            + b3.x * uv4 + b3.y * uv5 + b3.z * uv6 + b3.w * uv7;
            const float gxy = b4.x * uv0 + b4.y * uv1 + b4.z * uv2 + b4.w * uv3
                            + b5.x * uv4 + b5.y * uv5 + b5.z * uv6 + b5.w * uv7;
            const float exy = 0.5f * gxy;
            const float tr  = exx + eyy;
            const float tr3 = tr * (1.f / 3.f);
            const float dxx = exx - tr3, dyy = eyy - tr3, dzz = -tr3;
            const float dev2 = dxx * dxx + dyy * dyy + dzz * dzz + 2.f * exy * exy;
            const float trp = fmaxf(tr, 0.f), trn = fminf(tr, 0.f);
            const float psip = 0.5f * K_MOD * trp * trp + MU_ * dev2;
            const float psim = 0.5f * K_MOD * trn * trn;
            Eel += (psip * g + psim) * volA[ip];
        }
    }

    Eel = waveReduce(Eel);
    Efr = waveReduce(Efr);
    __shared__ float sE[4], sF[4];
    const int lane = threadIdx.x & 63, wid = threadIdx.x >> 6;
    if (lane == 0) { sE[wid] = Eel; sF[wid] = Efr; }
    __syncthreads();
    if (threadIdx.x == 0) {
        atomicAdd(&out[0], sE[0] + sE[1] + sE[2] + sE[3]);
        atomicAdd(&out[1], sF[0] + sF[1] + sF[2] + sF[3]);
    }
}

__global__ __launch_bounds__(256) void node_energy(
    const float* __restrict__ c, const float* __restrict__ prev_c,
    float* __restrict__ out)
{
    const int i = blockIdx.x * blockDim.x + threadIdx.x;
    float val = 0.f;
    if (i < N_NODES) {
        float d = prev_c[i] - c[i];
        d = fmaxf(d, 0.f);
        val = 0.5f * PENALTY * d * d;
    }
    val = waveReduce(val);
    __shared__ float sV[4];
    const int lane = threadIdx.x & 63, wid = threadIdx.x >> 6;
    if (lane == 0) sV[wid] = val;
    __syncthreads();
    if (threadIdx.x == 0) atomicAdd(&out[2], sV[0] + sV[1] + sV[2] + sV[3]);
}

extern "C" void kernel_launch(void* const* d_in, const int* in_sizes, int n_in,
                              void* d_out, int out_size, void* d_ws, size_t ws_size,
                              hipStream_t stream) {
    const float* u      = (const float*)d_in[0];
    const float* v      = (const float*)d_in[1];
    const float* c      = (const float*)d_in[2];
    const float* prev_c = (const float*)d_in[3];
    const int*   conn   = (const int*)d_in[4];
    const float* Nf     = (const float*)d_in[5];
    const float* dNdx   = (const float*)d_in[6];
    const float* B      = (const float*)d_in[7];
    const float* vol    = (const float*)d_in[8];
    float* out = (float*)d_out;

    hipMemsetAsync(out, 0, 3 * sizeof(float), stream);

    elem_energy<<<(N_ELEMS + 255) / 256, 256, 0, stream>>>(
        u, v, c, conn, Nf, dNdx, B, vol, out);
    node_energy<<<(N_NODES + 255) / 256, 256, 0, stream>>>(c, prev_c, out);
}